// Round 4
// baseline (186.877 us; speedup 1.0000x reference)
//
#include <hip/hip_runtime.h>
#include <math.h>

#define TT 2048
#define HH 128
#define ROWS 8
#define SP 132   // row-major LDS stride (qs, os)
#define XR 144   // chunk-padded LDS row stride: 4 chunks x 36
#define NBLK (TT / ROWS)

__device__ __forceinline__ float dot4(float4 a, float4 b) {
    return a.x * b.x + a.y * b.y + a.z * b.z + a.w * b.w;
}

// chunk-padded x index: element k of row r lives at r*XR + (k>>5)*36 + (k&31)
__device__ __forceinline__ int xidx(int r, int k) {
    return r * XR + ((k >> 5) * 36) + (k & 31);
}

// ---------------- prep: pack weights [k4][col] column-major + zero barrier ctrs ----
__global__ __launch_bounds__(256) void prep_kernel(
        const float* __restrict__ w_in, const float* __restrict__ w_out,
        const float* __restrict__ w_v, const float* __restrict__ w_q,
        const float* __restrict__ w_k, const float* __restrict__ w_o,
        const float* __restrict__ w_ff,
        float4* __restrict__ win_p, float4* __restrict__ wout_p,
        float4* __restrict__ wcat, float4* __restrict__ wff_p,
        unsigned* __restrict__ bar) {
    int i = blockIdx.x * 256 + threadIdx.x;
    if (blockIdx.x == 0 && threadIdx.x < 16) bar[threadIdx.x] = 0u;
    if (i < 4096) {
        int cg = i >> 7, col = i & 127;
        win_p[i] = ((const float4*)w_in)[col * 32 + cg];
    } else if (i < 8192) {
        int j = i - 4096, cg = j >> 7, col = j & 127;
        wout_p[j] = ((const float4*)w_out)[col * 32 + cg];
    } else if (i < 40960) {
        int j = i - 8192;
        int l = j >> 14, r = j & 16383, cg = r >> 9, col = r & 511;
        int sel = col >> 7, cm = col & 127;
        const float* s = (sel == 0 ? w_v : sel == 1 ? w_q : sel == 2 ? w_k : w_o) + l * HH * HH;
        wcat[j] = ((const float4*)s)[cm * 32 + cg];
    } else {
        int j = i - 40960;
        int l = j >> 13, r = j & 8191, cg = r >> 7, col = r & 127;
        const float* s = w_ff + l * HH * 256;
        wff_p[j] = ((const float4*)s)[col * 64 + cg];
    }
}

// ---- device-wide barrier: 256 blocks on 256 CUs, all co-resident. ----
__device__ __forceinline__ void grid_barrier(unsigned* __restrict__ ctr) {
    __syncthreads();
    if (threadIdx.x == 0) {
        __threadfence();
        atomicAdd(ctr, 1u);
        while (__hip_atomic_load(ctr, __ATOMIC_RELAXED, __HIP_MEMORY_SCOPE_AGENT)
               < (unsigned)NBLK) {
            __builtin_amdgcn_s_sleep(8);
        }
        __threadfence();
    }
    __syncthreads();
}

// ---- attention (waves 0-7): wave wv owns row t0+wv. kv fused float4, gi fused float2.
__device__ __forceinline__ void attn_row(int t0, const float* __restrict__ kvb,
        const float* __restrict__ qs, const float* __restrict__ os,
        const float* __restrict__ gib, float* __restrict__ hs) {
    int tid = threadIdx.x;
    int wv = tid >> 6, lane = tid & 63;
    if (wv >= 8) return;
    int t = t0 + wv;
    float2 q2 = *(const float2*)(qs + wv * SP + 2 * lane);
    float2 o2 = *(const float2*)(os + wv * SP + 2 * lane);
    int tp = t;
    float4 kv4 = *(const float4*)(kvb + tp * 256 + 4 * lane);  // (k0,v0,k1,v1)
    float2 gi2 = *(const float2*)(gib + 2 * tp);               // (g, iexp)
    float nx = 0.f, ny = 0.f, dsum = 0.f, decay = 1.f;
    while (true) {
        bool cont = (tp > 0) && (gi2.x != 0.f);
        float4 kvn = {0.f, 0.f, 0.f, 0.f};
        float2 gin = {0.f, 0.f};
        if (cont) {  // prefetch next step; overlaps the reduce below
            kvn = *(const float4*)(kvb + (tp - 1) * 256 + 4 * lane);
            gin = *(const float2*)(gib + 2 * (tp - 1));
        }
        float p = kv4.x * q2.x + kv4.z * q2.y;
#pragma unroll
        for (int off = 1; off <= 32; off <<= 1) p += __shfl_xor(p, off, 64);
        float coeff = decay * gi2.y * p;
        nx += coeff * kv4.y; ny += coeff * kv4.w; dsum += coeff;
        if (!cont) break;
        decay *= gi2.x;
        tp--; kv4 = kvn; gi2 = gin;
    }
    float inv = 1.f / fmaxf(fabsf(dsum), 1.f);
    int d = 2 * lane;
    *(float2*)(hs + wv * XR + (d >> 5) * 36 + (d & 31)) =
        make_float2(o2.x * nx * inv, o2.y * ny * inv);
}

// ---- f/i scalar gates (waves 0-7): wave wv handles row wv. ----
__device__ __forceinline__ void proj_fi(int t0, const float* __restrict__ xls,
        const float* __restrict__ w_f, const float* __restrict__ b_f,
        const float* __restrict__ w_i, const float* __restrict__ b_i,
        const int* __restrict__ start, float* __restrict__ gi) {
    int tid = threadIdx.x;
    int wv = tid >> 6, lane = tid & 63;
    if (wv >= 8) return;
    int d = 2 * lane;
    float2 xv = *(const float2*)(xls + wv * XR + (d >> 5) * 36 + (d & 31));
    float pf = xv.x * w_f[d] + xv.y * w_f[d + 1];
    float pi = xv.x * w_i[d] + xv.y * w_i[d + 1];
#pragma unroll
    for (int off = 1; off <= 32; off <<= 1) {
        pf += __shfl_xor(pf, off, 64);
        pi += __shfl_xor(pi, off, 64);
    }
    if (lane == 0) {
        int t = t0 + wv;
        gi[2 * t]     = start[t] ? 0.f : 1.f / (1.f + expf(-(pf + b_f[0])));
        gi[2 * t + 1] = expf(pi + b_i[0]);
    }
}

// ---- 4 projections, 16 waves: lane = (kc,4)x(c,16); wave = (rg,2)x(csg,8).
//      Each lane: 4 rows x 1 col-per-mat x 32 k. x4 read once feeds 4 mats. ----
__device__ __forceinline__ void proj_block(int t0, const float* __restrict__ xls,
        const float4* __restrict__ wc,
        const float* __restrict__ b_v, const float* __restrict__ b_q,
        const float* __restrict__ b_k, const float* __restrict__ b_o,
        float* __restrict__ kv, float* __restrict__ qs, float* __restrict__ os) {
    int tid = threadIdx.x;
    int lane = tid & 63, wv = tid >> 6;
    int kc = lane >> 4, c = lane & 15;
    int rg = wv >> 3, cslot = (wv & 7) * 16 + c;
    float acc[4][4] = {};  // [mat][row]
#pragma unroll
    for (int j = 0; j < 8; ++j) {
        const float4* wb = wc + (kc * 8 + j) * 512;
        float4 w0 = wb[cslot];
        float4 w1 = wb[128 + cslot];
        float4 w2 = wb[256 + cslot];
        float4 w3 = wb[384 + cslot];
#pragma unroll
        for (int rr = 0; rr < 4; ++rr) {
            float4 x4 = *(const float4*)(xls + (rg * 4 + rr) * XR + kc * 36 + 4 * j);
            acc[0][rr] += dot4(x4, w0);
            acc[1][rr] += dot4(x4, w1);
            acc[2][rr] += dot4(x4, w2);
            acc[3][rr] += dot4(x4, w3);
        }
    }
#pragma unroll
    for (int m = 0; m < 4; ++m)
#pragma unroll
        for (int rr = 0; rr < 4; ++rr) {
            acc[m][rr] += __shfl_xor(acc[m][rr], 16, 64);
            acc[m][rr] += __shfl_xor(acc[m][rr], 32, 64);
        }
    if (kc == 0) {
        const float ks = 0.088388347648318447f;  // 1/sqrt(128)
        float bv = b_v[cslot], bq = b_q[cslot], bk = b_k[cslot], bo = b_o[cslot];
#pragma unroll
        for (int rr = 0; rr < 4; ++rr) {
            int r = rg * 4 + rr, t = t0 + r;
            float kk = acc[2][rr] * ks + bk;
            float vv = acc[0][rr] + bv;
            *(float2*)(kv + t * 256 + 2 * cslot) = make_float2(kk, vv);
            qs[r * SP + cslot] = acc[1][rr] + bq;
            os[r * SP + cslot] = 1.f / (1.f + expf(-(acc[3][rr] + bo)));
        }
    }
}

// ---- ff: z = lrelu([h, e] @ w_ff.T + b_ff); 8-way K-split, 2 cols/lane. ----
__device__ __forceinline__ void ff_block(const float* __restrict__ hsb,
        const float* __restrict__ esb, const float4* __restrict__ wff,
        const float* __restrict__ b_ff, float* __restrict__ zs) {
    int tid = threadIdx.x;
    int lane = tid & 63, wv = tid >> 6;
    int kc = lane >> 3, c = lane & 7;           // kc 0..7 over k=256, c 0..7
    int rg = wv >> 3, cslot = (wv & 7) * 8 + c; // 0..63
    const float* xb = (kc < 4) ? hsb : esb;
    int ko = (kc & 3) * 36;
    float acc[2][4] = {};
#pragma unroll
    for (int j = 0; j < 8; ++j) {
        int k4 = kc * 8 + j;
        float4 w0 = wff[k4 * 128 + cslot];
        float4 w1 = wff[k4 * 128 + 64 + cslot];
#pragma unroll
        for (int rr = 0; rr < 4; ++rr) {
            float4 x4 = *(const float4*)(xb + (rg * 4 + rr) * XR + ko + 4 * j);
            acc[0][rr] += dot4(x4, w0);
            acc[1][rr] += dot4(x4, w1);
        }
    }
#pragma unroll
    for (int h = 0; h < 2; ++h)
#pragma unroll
        for (int rr = 0; rr < 4; ++rr) {
            float v = acc[h][rr];
            v += __shfl_xor(v, 8, 64);
            v += __shfl_xor(v, 16, 64);
            v += __shfl_xor(v, 32, 64);
            acc[h][rr] = v;
        }
    if (kc == 0) {
#pragma unroll
        for (int h = 0; h < 2; ++h) {
            int col = cslot + 64 * h;
            float bb = b_ff[col];
#pragma unroll
            for (int rr = 0; rr < 4; ++rr) {
                int r = rg * 4 + rr;
                float a = acc[h][rr] + bb;
                a = a > 0.f ? a : 0.01f * a;
                zs[xidx(r, col)] = a;
            }
        }
    }
}

// ---- 128->128 dense: 1 col/lane; ys (LDS chunk-padded) or yg (global). ----
__device__ __forceinline__ void dense128(int t0, const float* __restrict__ xls,
        const float4* __restrict__ Wp, const float* __restrict__ b,
        float* __restrict__ yg, float* __restrict__ ys) {
    int tid = threadIdx.x;
    int lane = tid & 63, wv = tid >> 6;
    int kc = lane >> 4, c = lane & 15;
    int rg = wv >> 3, cslot = (wv & 7) * 16 + c;
    float acc[4] = {};
#pragma unroll
    for (int j = 0; j < 8; ++j) {
        float4 w4 = Wp[(kc * 8 + j) * 128 + cslot];
#pragma unroll
        for (int rr = 0; rr < 4; ++rr) {
            float4 x4 = *(const float4*)(xls + (rg * 4 + rr) * XR + kc * 36 + 4 * j);
            acc[rr] += dot4(x4, w4);
        }
    }
#pragma unroll
    for (int rr = 0; rr < 4; ++rr) {
        acc[rr] += __shfl_xor(acc[rr], 16, 64);
        acc[rr] += __shfl_xor(acc[rr], 32, 64);
    }
    if (kc == 0) {
        float bb = b[cslot];
#pragma unroll
        for (int rr = 0; rr < 4; ++rr) {
            int r = rg * 4 + rr;
            float a = acc[rr] + bb;
            if (ys) ys[xidx(r, cslot)] = a;
            if (yg) yg[(t0 + r) * HH + cslot] = a;
        }
    }
}

// ---------------- fused: P0 | barrier | P1 | barrier | P2 ----------------
__global__ __launch_bounds__(1024, 1) void mega_kernel(
        const float* __restrict__ emb, const int* __restrict__ start,
        const float4* __restrict__ win_p, const float* __restrict__ b_in,
        const float4* __restrict__ wcat,
        const float* __restrict__ b_v, const float* __restrict__ b_q,
        const float* __restrict__ b_k, const float* __restrict__ b_o,
        const float* __restrict__ w_f, const float* __restrict__ b_f,
        const float* __restrict__ w_i, const float* __restrict__ b_i,
        const float4* __restrict__ wff_p, const float* __restrict__ b_ff,
        const float4* __restrict__ wout_p, const float* __restrict__ b_out,
        float* __restrict__ kv0, float* __restrict__ kv1,
        float* __restrict__ gi0, float* __restrict__ gi1,
        unsigned* __restrict__ bar,
        float* __restrict__ out) {
    __shared__ float xs[ROWS * XR];
    __shared__ float es[ROWS * XR];
    __shared__ float hs[ROWS * XR];
    __shared__ float zs[ROWS * XR];
    __shared__ float qs[ROWS * SP];
    __shared__ float os[ROWS * SP];
    int tid = threadIdx.x;
    int t0 = blockIdx.x * ROWS;

    // ---- P0: e (LDS only) + layer-0 projections ----
    {
        int row = tid >> 7, dd = tid & 127;
        xs[row * XR + (dd >> 5) * 36 + (dd & 31)] = emb[(t0 + row) * HH + dd];
    }
    __syncthreads();
    dense128(t0, xs, win_p, b_in, (float*)0, es);
    __syncthreads();
    proj_block(t0, es, wcat, b_v, b_q, b_k, b_o, kv0, qs, os);
    proj_fi(t0, es, w_f, b_f, w_i, b_i, start, gi0);
    grid_barrier(bar + 0);

    // ---- P1: attn0 + ff0 + layer-1 projections ----
    attn_row(t0, kv0, qs, os, gi0, hs);
    __syncthreads();
    ff_block(hs, es, wff_p, b_ff, zs);
    __syncthreads();
    proj_block(t0, zs, wcat + 16384, b_v + HH, b_q + HH, b_k + HH, b_o + HH,
               kv1, qs, os);
    proj_fi(t0, zs, w_f + HH, b_f + 1, w_i + HH, b_i + 1, start, gi1);
    grid_barrier(bar + 1);

    // ---- P2: attn1 + ff1 + final dense ----
    attn_row(t0, kv1, qs, os, gi1, hs);
    __syncthreads();
    ff_block(hs, es, wff_p + 8192, b_ff + HH, zs);
    __syncthreads();
    dense128(t0, zs, wout_p, b_out, out, (float*)0);
}

extern "C" void kernel_launch(void* const* d_in, const int* in_sizes, int n_in,
                              void* d_out, int out_size, void* d_ws, size_t ws_size,
                              hipStream_t stream) {
    const float* emb   = (const float*)d_in[0];
    const int*   start = (const int*)  d_in[1];
    const float* w_in  = (const float*)d_in[2];
    const float* b_in  = (const float*)d_in[3];
    const float* w_out = (const float*)d_in[4];
    const float* b_out = (const float*)d_in[5];
    const float* w_f   = (const float*)d_in[6];
    const float* b_f   = (const float*)d_in[7];
    const float* w_i   = (const float*)d_in[8];
    const float* b_i   = (const float*)d_in[9];
    const float* w_v   = (const float*)d_in[10];
    const float* b_v   = (const float*)d_in[11];
    const float* w_q   = (const float*)d_in[12];
    const float* b_q   = (const float*)d_in[13];
    const float* w_k   = (const float*)d_in[14];
    const float* b_k   = (const float*)d_in[15];
    const float* w_o   = (const float*)d_in[16];
    const float* b_o   = (const float*)d_in[17];
    const float* w_ff  = (const float*)d_in[18];
    const float* b_ff  = (const float*)d_in[19];
    float* out = (float*)d_out;

    unsigned* bar = (unsigned*)d_ws;            // 16 counters, zeroed by prep
    float* ws = (float*)d_ws + 64;
    float* kv0 = ws; ws += TT * 256;            // fused (k,v) interleaved per dim
    float* kv1 = ws; ws += TT * 256;
    float* gi0 = ws; ws += TT * 2;              // fused (g, iexp)
    float* gi1 = ws; ws += TT * 2;
    float4* win_p  = (float4*)ws; ws += 16384;   // 4096 float4
    float4* wout_p = (float4*)ws; ws += 16384;   // 4096 float4
    float4* wcat   = (float4*)ws; ws += 131072;  // 32768 float4 (2 layers)
    float4* wff_p  = (float4*)ws; ws += 65536;   // 16384 float4 (2 layers)

    prep_kernel<<<dim3(224), dim3(256), 0, stream>>>(
        w_in, w_out, w_v, w_q, w_k, w_o, w_ff, win_p, wout_p, wcat, wff_p, bar);
    mega_kernel<<<dim3(NBLK), dim3(1024), 0, stream>>>(
        emb, start, win_p, b_in, wcat,
        b_v, b_q, b_k, b_o, w_f, b_f, w_i, b_i,
        wff_p, b_ff, wout_p, b_out,
        kv0, kv1, gi0, gi1,
        bar, out);
}